// Round 8
// baseline (94.687 us; speedup 1.0000x reference)
//
#include <hip/hip_runtime.h>
#include <math.h>

#define NWIRES 6
#define DIM 64
#define NTOK 32768            // B*T = 16*2048
#define NBATCH 16
#define TPB 2048              // tokens per batch
#define NMOM 16               // Taylor order: exp(az), |az|<=sqrt(6); rem ~8e-8
#define SQRT6F 2.4494897427831781f
#define CSTRIDE 160           // per-circuit table stride (floats)

// ---------------------------------------------------------------------------
// Kernel 0: per-circuit tables.
// T[0..63]   = cos(d_b), T[64..127] = sin(d_b), d_b = sum_j (th_rx[j]/2)*(-1)^{b_j}
//   (RX layer = W diag(e^{-i d}) W; on real input: re0 = W cosd W psi,
//    im0 = W sind W psi up to sign/scale, both irrelevant to <Z>).
// T[128 + (layer*6+j)*2 + {0,1}] = {cos,sin}(th_ry/2), layer 0 = RY0, 1 = RY1.
// ---------------------------------------------------------------------------
__global__ void qsa_prep(const float* __restrict__ pq,
                         const float* __restrict__ pk,
                         const float* __restrict__ pv,
                         float* __restrict__ cs) {
    int b = threadIdx.x;      // 64 threads
    for (int circ = 0; circ < 3; ++circ) {
        const float* p = (circ == 0) ? pq : (circ == 1 ? pk : pv);
        float* T = cs + circ * CSTRIDE;
        float d = 0.f;
#pragma unroll
        for (int j = 0; j < 6; ++j)
            d += 0.5f * p[j] * ((b & (32 >> j)) ? -1.f : 1.f);
        float sd, cd;
        sincosf(d, &sd, &cd);
        T[b] = cd;
        T[64 + b] = sd;
        if (b < 12) {                       // p[6..11]=RY0, p[12..17]=RY1
            float s, c;
            sincosf(0.5f * p[6 + b], &s, &c);
            T[128 + b * 2 + 0] = c;
            T[128 + b * 2 + 1] = s;
        }
    }
}

// ---------------------------------------------------------------------------
// Real-state helpers: fully unrolled, compile-time indices, NO cross-lane.
// Wire j <-> bit (5-j), mask M = 32>>j.
// ---------------------------------------------------------------------------
template<int M>
__device__ __forceinline__ void whad(float* v) {       // Walsh butterfly stage
#pragma unroll
    for (int i = 0; i < DIM; ++i) {
        if (i & M) continue;
        int j = i | M;
        float a = v[i], b = v[j];
        v[i] = a + b;
        v[j] = a - b;
    }
}

template<int M>
__device__ __forceinline__ void ryr(float* v, float c, float s) {  // real RY
#pragma unroll
    for (int i = 0; i < DIM; ++i) {
        if (i & M) continue;
        int j = i | M;
        float a = v[i], b = v[j];
        v[i] = c * a - s * b;
        v[j] = s * a + c * b;
    }
}

template<int MC, int MT>
__device__ __forceinline__ void cnr(float* v) {        // real CNOT (rename)
#pragma unroll
    for (int i = 0; i < DIM; ++i) {
        if (!(i & MC) || (i & MT)) continue;
        int j = i | MT;
        float t = v[i]; v[i] = v[j]; v[j] = t;
    }
}

// ---------------------------------------------------------------------------
// Kernel 1: 2 threads per token (par=0 evolves re via cosd table, par=1 im
// via sind); blockIdx.y = circuit. Zero cross-lane until the final reduce.
// R7 post-mortem: live set ~90 VGPR never spills at any plausible cap, but
// residency was never PINNED multi-wave; R3 proved 1 wave/SIMD = 16% issue
// on this shape. waves_per_eu(3,3): cap 512/3=170 >= 90 (spill-impossible)
// AND guaranteed 3 resident waves/SIMD for latency hiding.
// Block=64: 4608 blocks -> 18/CU, no occupancy quantization tail.
// ---------------------------------------------------------------------------
__global__ __attribute__((amdgpu_waves_per_eu(3, 3)))
__launch_bounds__(64) void qsa_sim(
        const float* __restrict__ x,
        const float* __restrict__ cs,
        float* __restrict__ zq,
        float* __restrict__ kv) {
    int g = blockIdx.x * 64 + threadIdx.x;
    int par = g & 1;
    int token = g >> 1;
    int circ = blockIdx.y;
    const float* T = cs + circ * CSTRIDE;
    const float* P = T + 128;                 // RY cos/sin pairs

    float v[DIM];
    const float4* xp4 = (const float4*)(x + (size_t)token * DIM);
#pragma unroll
    for (int k = 0; k < DIM / 4; ++k) {
        float4 q = xp4[k];
        v[4*k+0] = q.x; v[4*k+1] = q.y; v[4*k+2] = q.z; v[4*k+3] = q.w;
    }

    // W psi
    whad<32>(v); whad<16>(v); whad<8>(v); whad<4>(v); whad<2>(v); whad<1>(v);
    // pointwise table (cosd for re-thread, sind for im-thread)
    const float4* tp4 = (const float4*)(T + par * 64);
#pragma unroll
    for (int k = 0; k < DIM / 4; ++k) {
        float4 q = tp4[k];
        v[4*k+0] *= q.x; v[4*k+1] *= q.y; v[4*k+2] *= q.z; v[4*k+3] *= q.w;
    }
    // W again -> state after full RX layer (this thread's re/im part)
    whad<32>(v); whad<16>(v); whad<8>(v); whad<4>(v); whad<2>(v); whad<1>(v);

    // RY0 layer (real rotations), wires 0..5
    ryr<32>(v, P[0],  P[1]);
    ryr<16>(v, P[2],  P[3]);
    ryr< 8>(v, P[4],  P[5]);
    ryr< 4>(v, P[6],  P[7]);
    ryr< 2>(v, P[8],  P[9]);
    ryr< 1>(v, P[10], P[11]);
    // CNOT ring (0,1)(1,2)(2,3)(3,4)(4,5)(5,0) — pure register renames
    cnr<32,16>(v);
    cnr<16, 8>(v);
    cnr< 8, 4>(v);
    cnr< 4, 2>(v);
    cnr< 2, 1>(v);
    cnr< 1,32>(v);
    // RY1 layer
    ryr<32>(v, P[12], P[13]);
    ryr<16>(v, P[14], P[15]);
    ryr< 8>(v, P[16], P[17]);
    ryr< 4>(v, P[18], P[19]);
    ryr< 2>(v, P[20], P[21]);
    ryr< 1>(v, P[22], P[23]);

    // <Z_w> = (2*S_w - norm)/norm; S_w, norm summed over re- and im-threads.
    if (circ < 2) {
        float nl = 0.f, s0 = 0.f;
#pragma unroll
        for (int i = 0; i < DIM; ++i) {
            float p2 = v[i] * v[i];
            nl += p2;
            if (!(i & 32)) s0 += p2;
        }
        float norm2 = nl + __shfl_xor(nl, 1, 64);
        float S0 = s0 + __shfl_xor(s0, 1, 64);
        float z0 = (2.f * S0 - norm2) / norm2;
        if (par == 0) {
            if (circ == 0) zq[token] = SQRT6F * z0;   // a_t, natural-exp scale
            else           kv[(size_t)token * 8] = z0;
        }
    } else {
        float nl = 0.f, s0=0.f, s1=0.f, s2=0.f, s3=0.f, s4=0.f, s5=0.f;
#pragma unroll
        for (int i = 0; i < DIM; ++i) {
            float p2 = v[i] * v[i];
            nl += p2;
            if (!(i & 32)) s0 += p2;
            if (!(i & 16)) s1 += p2;
            if (!(i &  8)) s2 += p2;
            if (!(i &  4)) s3 += p2;
            if (!(i &  2)) s4 += p2;
            if (!(i &  1)) s5 += p2;
        }
        float norm2 = nl + __shfl_xor(nl, 1, 64);
        float S0 = s0 + __shfl_xor(s0, 1, 64);
        float S1 = s1 + __shfl_xor(s1, 1, 64);
        float S2 = s2 + __shfl_xor(s2, 1, 64);
        float S3 = s3 + __shfl_xor(s3, 1, 64);
        float S4 = s4 + __shfl_xor(s4, 1, 64);
        float S5 = s5 + __shfl_xor(s5, 1, 64);
        float inv = 1.0f / norm2;
        float* o = kv + (size_t)token * 8;
        if (par == 0) {
            o[1] = (2.f*S0 - norm2) * inv;
            o[2] = (2.f*S1 - norm2) * inv;
            o[3] = (2.f*S2 - norm2) * inv;
        } else {
            o[4] = (2.f*S3 - norm2) * inv;
            o[5] = (2.f*S4 - norm2) * inv;
            o[6] = (2.f*S5 - norm2) * inv;
        }
    }
}

// ---------------------------------------------------------------------------
// Kernel 2: partial power moments per (batch, chunk-of-256).
// S_m = sum z^m, H_{m,w} = sum z^m * v_w, m=0..15.  112 register accumulators,
// butterfly-reduced across the wave; lane 0 stores 112 floats.
// ---------------------------------------------------------------------------
__global__ __attribute__((amdgpu_waves_per_eu(1, 2)))
__launch_bounds__(64) void qsa_moments_partial(
        const float* __restrict__ kv,
        float* __restrict__ mpart) {
    int blk = blockIdx.x;             // 16 batches * 8 chunks
    int b = blk >> 3, c = blk & 7;
    int lane = threadIdx.x;
    float S[NMOM], H[NMOM][6];
#pragma unroll
    for (int m = 0; m < NMOM; ++m) {
        S[m] = 0.f;
#pragma unroll
        for (int w = 0; w < 6; ++w) H[m][w] = 0.f;
    }
    const float* base = kv + ((size_t)(b * TPB + c * 256)) * 8;
#pragma unroll
    for (int r = 0; r < 4; ++r) {
        const float4* e = (const float4*)(base + (size_t)(r * 64 + lane) * 8);
        float4 e0 = e[0], e1 = e[1];
        float z = e0.x;
        float v0 = e0.y, v1 = e0.z, v2 = e0.w, v3 = e1.x, v4 = e1.y, v5 = e1.z;
        float pw = 1.f;
#pragma unroll
        for (int m = 0; m < NMOM; ++m) {
            S[m] += pw;
            H[m][0] += pw * v0; H[m][1] += pw * v1; H[m][2] += pw * v2;
            H[m][3] += pw * v3; H[m][4] += pw * v4; H[m][5] += pw * v5;
            pw *= z;
        }
    }
#pragma unroll
    for (int d = 32; d >= 1; d >>= 1) {
#pragma unroll
        for (int m = 0; m < NMOM; ++m) {
            S[m] += __shfl_xor(S[m], d, 64);
#pragma unroll
            for (int w = 0; w < 6; ++w) H[m][w] += __shfl_xor(H[m][w], d, 64);
        }
    }
    if (lane == 0) {
        float* o = mpart + (size_t)blk * 112;
#pragma unroll
        for (int m = 0; m < NMOM; ++m) {
            float* om = o + m * 7;
            om[0] = S[m];
            om[1] = H[m][0]; om[2] = H[m][1]; om[3] = H[m][2];
            om[4] = H[m][3]; om[5] = H[m][4]; om[6] = H[m][5];
        }
    }
}

// ---------------------------------------------------------------------------
// Kernel 3: fused combine + per-token evaluation (one block = 256 tokens,
// all in one batch). Stage-1: reduce this batch's 8 chunk-partials into LDS.
// Stage-2: den = sum_m p_m S_m, out_w = sum_m p_m H_mw, p_m = a^m/m!.
// LDS reads in the poly loop are wave-uniform broadcasts (conflict-free).
// ---------------------------------------------------------------------------
__global__ __launch_bounds__(256) void qsa_eval(
        const float* __restrict__ zq,
        const float* __restrict__ mpart,
        float* __restrict__ out) {
    __shared__ float sm[112];
    int bk = blockIdx.x;                      // 128 blocks
    int b = bk >> 3;                          // 8 blocks per batch
    int tid = threadIdx.x;
    if (tid < 112) {
        float s = 0.f;
#pragma unroll
        for (int c = 0; c < 8; ++c) s += mpart[(size_t)(b * 8 + c) * 112 + tid];
        sm[tid] = s;
    }
    __syncthreads();

    int t = bk * 256 + tid;
    float a = zq[t];
    float den = 0.f, o0 = 0.f, o1 = 0.f, o2 = 0.f, o3 = 0.f, o4 = 0.f, o5 = 0.f;
    float pw = 1.f;
#pragma unroll
    for (int m = 0; m < NMOM; ++m) {
        const float* mm = sm + m * 7;
        den += pw * mm[0];
        o0 += pw * mm[1]; o1 += pw * mm[2]; o2 += pw * mm[3];
        o3 += pw * mm[4]; o4 += pw * mm[5]; o5 += pw * mm[6];
        pw *= a * (1.0f / (m + 1));           // p_{m+1} = p_m * a/(m+1)
    }
    float inv = 1.0f / den;
    float* o = out + (size_t)t * 6;
    float2* o2p = (float2*)o;                 // t*24B is 8-aligned
    o2p[0] = make_float2(o0 * inv, o1 * inv);
    o2p[1] = make_float2(o2 * inv, o3 * inv);
    o2p[2] = make_float2(o4 * inv, o5 * inv);
}

// ---------------------------------------------------------------------------
extern "C" void kernel_launch(void* const* d_in, const int* in_sizes, int n_in,
                              void* d_out, int out_size, void* d_ws, size_t ws_size,
                              hipStream_t stream) {
    const float* x  = (const float*)d_in[0];
    const float* pq = (const float*)d_in[1];
    const float* pk = (const float*)d_in[2];
    const float* pv = (const float*)d_in[3];
    float* w = (float*)d_ws;
    // ws (floats): cs[512] | zq[32768] | kv[262144] | mpart[128*112]
    float* cs    = w;
    float* zq    = w + 512;
    float* kv    = w + 512 + NTOK;
    float* mpart = w + 512 + NTOK + NTOK * 8;
    float* out   = (float*)d_out;

    qsa_prep<<<1, 64, 0, stream>>>(pq, pk, pv, cs);
    qsa_sim<<<dim3(NTOK * 2 / 64, 3), 64, 0, stream>>>(x, cs, zq, kv);
    qsa_moments_partial<<<NBATCH * 8, 64, 0, stream>>>(kv, mpart);
    qsa_eval<<<NTOK / 256, 256, 0, stream>>>(zq, mpart, out);
}